// Round 3
// baseline (243.068 us; speedup 1.0000x reference)
//
#include <hip/hip_runtime.h>
#include <hip/hip_bf16.h>
#include <stdint.h>

typedef unsigned short u16;
typedef __attribute__((ext_vector_type(8))) short short8;
typedef __attribute__((ext_vector_type(4))) float f32x4;

#define BATCH 4096
// output region offsets (f32 elements) in d_out: out, h_mix, out_k, h_k
#define OFF_OUT  0
#define OFF_HMIX (BATCH * 256)
#define OFF_OK   (OFF_HMIX + BATCH * 512)
#define OFF_HK   (OFF_OK + BATCH * 256 * 8)

// ws layout (bf16 elements): xb, hb, Wihb, Whhb, Woutb  (~17 MB total)
#define WS_XB   0
#define WS_HB   (2097152)
#define WS_WIH  (4194304)
#define WS_WHH  (6291456)
#define WS_WOUT (8388608)

__device__ __forceinline__ u16 f2b(float f) {
  union { float f; uint32_t u; } c; c.f = f;
  uint32_t u = c.u;
  return (u16)((u + 0x7fffu + ((u >> 16) & 1u)) >> 16);  // RNE
}

// async global->LDS, 16B per lane. LDS dest = wave-uniform base + lane*16.
__device__ __forceinline__ void gload16(const u16* g, u16* l) {
  __builtin_amdgcn_global_load_lds(
      (const __attribute__((address_space(1))) void*)g,
      (__attribute__((address_space(3))) void*)l, 16, 0, 0);
}

// ---------------------------------------------------------------------------
// K0: f32 -> bf16 conversion of x, h, W_ih, W_hh, W_out into ws.
// Index space: float4 units. 2,129,920 total = 8320 blocks x 256.
// ---------------------------------------------------------------------------
__global__ __launch_bounds__(256) void k0_cvt(
    const float* __restrict__ x, const float* __restrict__ h,
    const float* __restrict__ Wih, const float* __restrict__ Whh,
    const float* __restrict__ Wout, u16* __restrict__ ws) {
  const int i = blockIdx.x * 256 + threadIdx.x;
  const float* src; int j; size_t dst;
  if      (i <  524288) { src = x;    j = i;           dst = WS_XB;   }
  else if (i < 1048576) { src = h;    j = i -  524288; dst = WS_HB;   }
  else if (i < 1572864) { src = Wih;  j = i - 1048576; dst = WS_WIH;  }
  else if (i < 2097152) { src = Whh;  j = i - 1572864; dst = WS_WHH;  }
  else                  { src = Wout; j = i - 2097152; dst = WS_WOUT; }
  const float4 v = ((const float4*)src)[j];
  ushort4 o;
  o.x = f2b(v.x); o.y = f2b(v.y); o.z = f2b(v.z); o.w = f2b(v.w);
  ((ushort4*)(ws + dst))[j] = o;
}

// ---------------------------------------------------------------------------
// K1: T[b][k*512+n] = tanh( x[b]·W_ih[k][n] + h[b]·W_hh[k][n] )
// One 4096x4096x1024 bf16 GEMM (C = A·B^T), tanh epilogue, f32 plane layout
// into the d_out h_k region. 128x128 tile, BK=64, 4 waves 2x2, 16x16x32 MFMA.
// ---------------------------------------------------------------------------
__global__ __launch_bounds__(256) void k1_gemm_tanh(
    const u16* __restrict__ xb, const u16* __restrict__ hb,
    const u16* __restrict__ Wih, const u16* __restrict__ Whh,
    float* __restrict__ T) {
  __shared__ u16 As[128 * 64];
  __shared__ u16 Bs[128 * 64];
  const int tid  = threadIdx.x;
  const int lane = tid & 63;
  const int w    = tid >> 6;
  const int wm   = w >> 1, wn = w & 1;
  const int row0 = blockIdx.x * 128;
  const int col0 = blockIdx.y * 128;   // j = k*512 + n; 128 | 512 so tile is single-k
  const int kk   = col0 >> 9;
  const int nh0  = col0 & 511;
  const int sr   = tid >> 3;           // 0..31 staging row in 32-row round
  const int sc   = (tid & 7) * 8;      // staging col (elements)
  const int ldsw = (w * 8) * 64;       // wave-uniform LDS base (elements)

  const u16* WihK = Wih + (size_t)kk * 512 * 512;
  const u16* WhhK = Whh + (size_t)kk * 512 * 512;

  f32x4 acc[4][4] = {};

  for (int kt = 0; kt < 16; ++kt) {
    const int kb = kt * 64;
    const u16* Asrc; const u16* Bsrc; int ko;
    if (kb < 512) { Asrc = xb; Bsrc = WihK; ko = kb; }
    else          { Asrc = hb; Bsrc = WhhK; ko = kb - 512; }
#pragma unroll
    for (int ro = 0; ro < 4; ++ro) {
      gload16(Asrc + (size_t)(row0 + ro * 32 + sr) * 512 + ko + sc, &As[ro * 32 * 64 + ldsw]);
      gload16(Bsrc + (size_t)(nh0  + ro * 32 + sr) * 512 + ko + sc, &Bs[ro * 32 * 64 + ldsw]);
    }
    __syncthreads();
#pragma unroll
    for (int ks = 0; ks < 2; ++ks) {
      const int koff = ks * 32 + (lane >> 4) * 8;
      short8 af[4], bf[4];
#pragma unroll
      for (int i = 0; i < 4; ++i)
        af[i] = *(const short8*)&As[(wm * 64 + i * 16 + (lane & 15)) * 64 + koff];
#pragma unroll
      for (int j = 0; j < 4; ++j)
        bf[j] = *(const short8*)&Bs[(wn * 64 + j * 16 + (lane & 15)) * 64 + koff];
#pragma unroll
      for (int i = 0; i < 4; ++i)
#pragma unroll
        for (int j = 0; j < 4; ++j)
          acc[i][j] = __builtin_amdgcn_mfma_f32_16x16x32_bf16(af[i], bf[j], acc[i][j], 0, 0, 0);
    }
    __syncthreads();
  }

  const int quad = lane >> 4, cl = lane & 15;
#pragma unroll
  for (int i = 0; i < 4; ++i)
#pragma unroll
    for (int j = 0; j < 4; ++j)
#pragma unroll
      for (int r = 0; r < 4; ++r) {
        const int rr = row0 + wm * 64 + i * 16 + quad * 4 + r;
        const int cc = col0 + wn * 64 + j * 16 + cl;
        const float v = acc[i][j][r];
        // tanh(v) = 1 - 2/(e^{2v}+1); saturates to +/-1, no NaN for finite v
        const float e = __expf(2.0f * v);
        T[(size_t)rr * 4096 + cc] = 1.0f - 2.0f / (e + 1.0f);
      }
}

// ---------------------------------------------------------------------------
// K2: O[b][k*256+y] = sum_n T[b][k*512+n] * W_out[y][n]   (8 batched GEMMs)
// A source is the f32 T plane: manual stage+convert to bf16 LDS.
// grid (32 btiles, 2 ytiles, 8 k). f32 plane layout into d_out out_k region.
// ---------------------------------------------------------------------------
__global__ __launch_bounds__(256) void k2_gemm_out(
    const float* __restrict__ T, const u16* __restrict__ Wout,
    float* __restrict__ O) {
  __shared__ u16 As[128 * 64];
  __shared__ u16 Bs[128 * 64];
  const int tid  = threadIdx.x;
  const int lane = tid & 63;
  const int w    = tid >> 6;
  const int wm   = w >> 1, wn = w & 1;
  const int row0 = blockIdx.x * 128;
  const int y0   = blockIdx.y * 128;
  const int kk   = blockIdx.z;
  const int sr   = tid >> 3;
  const int sc   = (tid & 7) * 8;
  const int ldsw = (w * 8) * 64;

  f32x4 acc[4][4] = {};

  for (int kt = 0; kt < 8; ++kt) {
    const int kb = kt * 64;
#pragma unroll
    for (int ro = 0; ro < 4; ++ro) {
      // A: f32 plane -> convert -> LDS (plain ds_write_b128)
      const float* src = T + (size_t)(row0 + ro * 32 + sr) * 4096 + kk * 512 + kb + sc;
      const float4 v0 = *(const float4*)(src);
      const float4 v1 = *(const float4*)(src + 4);
      short8 cv;
      cv[0] = (short)f2b(v0.x); cv[1] = (short)f2b(v0.y);
      cv[2] = (short)f2b(v0.z); cv[3] = (short)f2b(v0.w);
      cv[4] = (short)f2b(v1.x); cv[5] = (short)f2b(v1.y);
      cv[6] = (short)f2b(v1.z); cv[7] = (short)f2b(v1.w);
      *(short8*)&As[(ro * 32 + sr) * 64 + sc] = cv;
      // B: bf16 async direct-to-LDS
      gload16(Wout + (size_t)(y0 + ro * 32 + sr) * 512 + kb + sc,
              &Bs[ro * 32 * 64 + ldsw]);
    }
    __syncthreads();
#pragma unroll
    for (int ks = 0; ks < 2; ++ks) {
      const int koff = ks * 32 + (lane >> 4) * 8;
      short8 af[4], bf[4];
#pragma unroll
      for (int i = 0; i < 4; ++i)
        af[i] = *(const short8*)&As[(wm * 64 + i * 16 + (lane & 15)) * 64 + koff];
#pragma unroll
      for (int j = 0; j < 4; ++j)
        bf[j] = *(const short8*)&Bs[(wn * 64 + j * 16 + (lane & 15)) * 64 + koff];
#pragma unroll
      for (int i = 0; i < 4; ++i)
#pragma unroll
        for (int j = 0; j < 4; ++j)
          acc[i][j] = __builtin_amdgcn_mfma_f32_16x16x32_bf16(af[i], bf[j], acc[i][j], 0, 0, 0);
    }
    __syncthreads();
  }

  const int quad = lane >> 4, cl = lane & 15;
#pragma unroll
  for (int i = 0; i < 4; ++i)
#pragma unroll
    for (int j = 0; j < 4; ++j)
#pragma unroll
      for (int r = 0; r < 4; ++r) {
        const int rr = row0 + wm * 64 + i * 16 + quad * 4 + r;
        const int cc = y0 + wn * 64 + j * 16 + cl;
        O[(size_t)rr * 2048 + kk * 256 + cc] = acc[i][j][r];
      }
}

// ---------------------------------------------------------------------------
// K3: per-row in-place permute plane->interleaved (f32) + belief mix.
// Block b: reads T row (4096 f32) & O row (2048 f32) into regs, barrier,
// writes h_k[b][n][k] / out_k[b][y][k] as float4 pairs + h_mix / out.
// ---------------------------------------------------------------------------
__global__ __launch_bounds__(512) void k3_epi(const float* __restrict__ pi,
                                              float* __restrict__ dout) {
  const int b   = blockIdx.x;
  const int tid = threadIdx.x;
  float* T = dout + OFF_HK;
  float* O = dout + OFF_OK;

  float pif[8];
#pragma unroll
  for (int k = 0; k < 8; ++k) pif[k] = pi[b * 8 + k];

  float tv[8]; float hm = 0.0f;
#pragma unroll
  for (int k = 0; k < 8; ++k) {
    const float v = T[(size_t)b * 4096 + k * 512 + tid];
    tv[k] = v; hm += pif[k] * v;
  }
  float ov[8]; float om = 0.0f;
  if (tid < 256) {
#pragma unroll
    for (int k = 0; k < 8; ++k) {
      const float v = O[(size_t)b * 2048 + k * 256 + tid];
      ov[k] = v; om += pif[k] * v;
    }
  }
  __syncthreads();  // all plane reads done before any in-place writes

  float4* tw = (float4*)&T[(size_t)b * 4096 + tid * 8];
  tw[0] = make_float4(tv[0], tv[1], tv[2], tv[3]);
  tw[1] = make_float4(tv[4], tv[5], tv[6], tv[7]);
  dout[OFF_HMIX + (size_t)b * 512 + tid] = hm;

  if (tid < 256) {
    float4* ow = (float4*)&O[(size_t)b * 2048 + tid * 8];
    ow[0] = make_float4(ov[0], ov[1], ov[2], ov[3]);
    ow[1] = make_float4(ov[4], ov[5], ov[6], ov[7]);
    dout[OFF_OUT + (size_t)b * 256 + tid] = om;
  }
}

extern "C" void kernel_launch(void* const* d_in, const int* in_sizes, int n_in,
                              void* d_out, int out_size, void* d_ws, size_t ws_size,
                              hipStream_t stream) {
  const float* x    = (const float*)d_in[0];
  const float* h    = (const float*)d_in[1];
  const float* pi   = (const float*)d_in[2];
  const float* Wih  = (const float*)d_in[3];
  const float* Whh  = (const float*)d_in[4];
  const float* Wout = (const float*)d_in[5];
  float* out = (float*)d_out;
  u16* ws  = (u16*)d_ws;
  float* T = out + OFF_HK;  // h_k region doubles as f32 plane scratch
  float* O = out + OFF_OK;  // out_k region doubles as f32 plane scratch

  k0_cvt<<<dim3(8320), 256, 0, stream>>>(x, h, Wih, Whh, Wout, ws);
  k1_gemm_tanh<<<dim3(32, 32), 256, 0, stream>>>(
      ws + WS_XB, ws + WS_HB, ws + WS_WIH, ws + WS_WHH, T);
  k2_gemm_out<<<dim3(32, 2, 8), 256, 0, stream>>>(T, ws + WS_WOUT, O);
  k3_epi<<<dim3(BATCH), 512, 0, stream>>>(pi, out);
}

// Round 4
// 226.683 us; speedup vs baseline: 1.0723x; 1.0723x over previous
//
#include <hip/hip_runtime.h>
#include <hip/hip_bf16.h>
#include <stdint.h>

typedef unsigned short u16;
typedef __attribute__((ext_vector_type(8))) short short8;
typedef __attribute__((ext_vector_type(4))) float f32x4;

#define BATCH 4096
// output region offsets (f32 elements) in d_out: out, h_mix, out_k, h_k
#define OFF_OUT  0
#define OFF_HMIX (BATCH * 256)
#define OFF_OK   (OFF_HMIX + BATCH * 512)
#define OFF_HK   (OFF_OK + BATCH * 256 * 8)

// ws layout (u16/bf16 elements): xb, hb, Wihb, Whhb, Woutb, Tb (~50.5 MB total)
#define WS_XB   0
#define WS_HB   (2097152)
#define WS_WIH  (4194304)
#define WS_WHH  (6291456)
#define WS_WOUT (8388608)
#define WS_T    (8519680)   // 4096x4096 bf16 plane, 33.5 MB

__device__ __forceinline__ float b2f(u16 v) {
  union { uint32_t u; float f; } c; c.u = ((uint32_t)v) << 16; return c.f;
}
__device__ __forceinline__ u16 f2b(float f) {
  union { float f; uint32_t u; } c; c.f = f;
  uint32_t u = c.u;
  return (u16)((u + 0x7fffu + ((u >> 16) & 1u)) >> 16);  // RNE
}

// async global->LDS, 16B per lane. LDS dest = wave-uniform base + lane*16.
__device__ __forceinline__ void gload16(const u16* g, u16* l) {
  __builtin_amdgcn_global_load_lds(
      (const __attribute__((address_space(1))) void*)g,
      (__attribute__((address_space(3))) void*)l, 16, 0, 0);
}

// ---------------------------------------------------------------------------
// K0: f32 -> bf16 conversion of x, h, W_ih, W_hh, W_out into ws.
// ---------------------------------------------------------------------------
__global__ __launch_bounds__(256) void k0_cvt(
    const float* __restrict__ x, const float* __restrict__ h,
    const float* __restrict__ Wih, const float* __restrict__ Whh,
    const float* __restrict__ Wout, u16* __restrict__ ws) {
  const int i = blockIdx.x * 256 + threadIdx.x;
  const float* src; int j; size_t dst;
  if      (i <  524288) { src = x;    j = i;           dst = WS_XB;   }
  else if (i < 1048576) { src = h;    j = i -  524288; dst = WS_HB;   }
  else if (i < 1572864) { src = Wih;  j = i - 1048576; dst = WS_WIH;  }
  else if (i < 2097152) { src = Whh;  j = i - 1572864; dst = WS_WHH;  }
  else                  { src = Wout; j = i - 2097152; dst = WS_WOUT; }
  const float4 v = ((const float4*)src)[j];
  ushort4 o;
  o.x = f2b(v.x); o.y = f2b(v.y); o.z = f2b(v.z); o.w = f2b(v.w);
  ((ushort4*)(ws + dst))[j] = o;
}

// ---------------------------------------------------------------------------
// K1: Tb[b][k*512+n] = tanh( x[b]·W_ih[k][n] + h[b]·W_hh[k][n] )  (bf16 plane)
// 4096x4096x1024 bf16 GEMM, tanh epilogue. 128x128 tile, BK=64, 4 waves 2x2.
// LDS chunk XOR swizzle: slot (r, c') holds global chunk c'^(r&7); the async
// DMA can't scatter LDS, so the *global source column* is permuted per lane.
// Fragment reads then hit each bank with exactly 2 lanes (free on CDNA4).
// ---------------------------------------------------------------------------
__global__ __launch_bounds__(256) void k1_gemm_tanh(
    const u16* __restrict__ xb, const u16* __restrict__ hb,
    const u16* __restrict__ Wih, const u16* __restrict__ Whh,
    u16* __restrict__ Tb) {
  __shared__ u16 As[128 * 64];
  __shared__ u16 Bs[128 * 64];
  const int tid  = threadIdx.x;
  const int lane = tid & 63;
  const int w    = tid >> 6;
  const int wm   = w >> 1, wn = w & 1;
  const int row0 = blockIdx.x * 128;
  const int col0 = blockIdx.y * 128;   // j = k*512 + n; 128 | 512 so tile is single-k
  const int kk   = col0 >> 9;
  const int nh0  = col0 & 511;
  const int sr   = tid >> 3;                                  // 0..31 staging row
  const int sc   = ((tid & 7) ^ ((tid >> 3) & 7)) * 8;        // swizzled source col
  const int ldsw = (w * 8) * 64;

  const u16* WihK = Wih + (size_t)kk * 512 * 512;
  const u16* WhhK = Whh + (size_t)kk * 512 * 512;

  f32x4 acc[4][4] = {};

  for (int kt = 0; kt < 16; ++kt) {
    const int kb = kt * 64;
    const u16* Asrc; const u16* Bsrc; int ko;
    if (kb < 512) { Asrc = xb; Bsrc = WihK; ko = kb; }
    else          { Asrc = hb; Bsrc = WhhK; ko = kb - 512; }
#pragma unroll
    for (int ro = 0; ro < 4; ++ro) {
      gload16(Asrc + (size_t)(row0 + ro * 32 + sr) * 512 + ko + sc, &As[ro * 32 * 64 + ldsw]);
      gload16(Bsrc + (size_t)(nh0  + ro * 32 + sr) * 512 + ko + sc, &Bs[ro * 32 * 64 + ldsw]);
    }
    __syncthreads();
    const int l7 = lane & 7, quad = lane >> 4, rl = lane & 15;
#pragma unroll
    for (int ks = 0; ks < 2; ++ks) {
      short8 af[4], bf[4];
      const int cs = ((ks * 4 + quad) ^ l7) * 8;  // swizzled chunk offset (elements)
#pragma unroll
      for (int i = 0; i < 4; ++i)
        af[i] = *(const short8*)&As[(wm * 64 + i * 16 + rl) * 64 + cs];
#pragma unroll
      for (int j = 0; j < 4; ++j)
        bf[j] = *(const short8*)&Bs[(wn * 64 + j * 16 + rl) * 64 + cs];
#pragma unroll
      for (int i = 0; i < 4; ++i)
#pragma unroll
        for (int j = 0; j < 4; ++j)
          acc[i][j] = __builtin_amdgcn_mfma_f32_16x16x32_bf16(af[i], bf[j], acc[i][j], 0, 0, 0);
    }
    __syncthreads();
  }

  const int quad = lane >> 4, cl = lane & 15;
#pragma unroll
  for (int i = 0; i < 4; ++i)
#pragma unroll
    for (int j = 0; j < 4; ++j)
#pragma unroll
      for (int r = 0; r < 4; ++r) {
        const int rr = row0 + wm * 64 + i * 16 + quad * 4 + r;
        const int cc = col0 + wn * 64 + j * 16 + cl;
        const float v = acc[i][j][r];
        // tanh(v) = 1 - 2/(e^{2v}+1); saturates to +/-1, no NaN for finite v
        const float e = __expf(2.0f * v);
        Tb[(size_t)rr * 4096 + cc] = f2b(1.0f - 2.0f / (e + 1.0f));
      }
}

// ---------------------------------------------------------------------------
// K2: O[b][k*256+y] = sum_n Tb[b][k*512+n] * Wout[y][n]   (8 batched GEMMs)
// Pure async-bf16 staging (m97-style), swizzled. f32 plane into out_k region.
// ---------------------------------------------------------------------------
__global__ __launch_bounds__(256) void k2_gemm_out(
    const u16* __restrict__ Tb, const u16* __restrict__ Wout,
    float* __restrict__ O) {
  __shared__ u16 As[128 * 64];
  __shared__ u16 Bs[128 * 64];
  const int tid  = threadIdx.x;
  const int lane = tid & 63;
  const int w    = tid >> 6;
  const int wm   = w >> 1, wn = w & 1;
  const int row0 = blockIdx.x * 128;
  const int y0   = blockIdx.y * 128;
  const int kk   = blockIdx.z;
  const int sr   = tid >> 3;
  const int sc   = ((tid & 7) ^ ((tid >> 3) & 7)) * 8;
  const int ldsw = (w * 8) * 64;

  f32x4 acc[4][4] = {};

  for (int kt = 0; kt < 8; ++kt) {
    const int kb = kt * 64;
#pragma unroll
    for (int ro = 0; ro < 4; ++ro) {
      gload16(Tb + (size_t)(row0 + ro * 32 + sr) * 4096 + kk * 512 + kb + sc,
              &As[ro * 32 * 64 + ldsw]);
      gload16(Wout + (size_t)(y0 + ro * 32 + sr) * 512 + kb + sc,
              &Bs[ro * 32 * 64 + ldsw]);
    }
    __syncthreads();
    const int l7 = lane & 7, quad = lane >> 4, rl = lane & 15;
#pragma unroll
    for (int ks = 0; ks < 2; ++ks) {
      short8 af[4], bf[4];
      const int cs = ((ks * 4 + quad) ^ l7) * 8;
#pragma unroll
      for (int i = 0; i < 4; ++i)
        af[i] = *(const short8*)&As[(wm * 64 + i * 16 + rl) * 64 + cs];
#pragma unroll
      for (int j = 0; j < 4; ++j)
        bf[j] = *(const short8*)&Bs[(wn * 64 + j * 16 + rl) * 64 + cs];
#pragma unroll
      for (int i = 0; i < 4; ++i)
#pragma unroll
        for (int j = 0; j < 4; ++j)
          acc[i][j] = __builtin_amdgcn_mfma_f32_16x16x32_bf16(af[i], bf[j], acc[i][j], 0, 0, 0);
    }
    __syncthreads();
  }

  const int quad = lane >> 4, cl = lane & 15;
#pragma unroll
  for (int i = 0; i < 4; ++i)
#pragma unroll
    for (int j = 0; j < 4; ++j)
#pragma unroll
      for (int r = 0; r < 4; ++r) {
        const int rr = row0 + wm * 64 + i * 16 + quad * 4 + r;
        const int cc = y0 + wn * 64 + j * 16 + cl;
        O[(size_t)rr * 2048 + kk * 256 + cc] = acc[i][j][r];
      }
}

// ---------------------------------------------------------------------------
// K3: epilogue. Block b: reads Tb row (bf16, from ws) and O row (f32 plane),
// writes h_k f32 interleaved (no race: source in ws), permutes O in place
// (reads->barrier->writes), emits h_mix and out.
// ---------------------------------------------------------------------------
__global__ __launch_bounds__(512) void k3_epi(const float* __restrict__ pi,
                                              const u16* __restrict__ Tb,
                                              float* __restrict__ dout) {
  const int b   = blockIdx.x;
  const int tid = threadIdx.x;
  float* O = dout + OFF_OK;

  float pif[8];
#pragma unroll
  for (int k = 0; k < 8; ++k) pif[k] = pi[b * 8 + k];

  float tv[8]; float hm = 0.0f;
#pragma unroll
  for (int k = 0; k < 8; ++k) {
    const float v = b2f(Tb[(size_t)b * 4096 + k * 512 + tid]);
    tv[k] = v; hm += pif[k] * v;
  }
  float ov[8]; float om = 0.0f;
  if (tid < 256) {
#pragma unroll
    for (int k = 0; k < 8; ++k) {
      const float v = O[(size_t)b * 2048 + k * 256 + tid];
      ov[k] = v; om += pif[k] * v;
    }
  }
  __syncthreads();  // O-plane reads complete before in-place writes

  float4* tw = (float4*)&dout[OFF_HK + (size_t)b * 4096 + tid * 8];
  tw[0] = make_float4(tv[0], tv[1], tv[2], tv[3]);
  tw[1] = make_float4(tv[4], tv[5], tv[6], tv[7]);
  dout[OFF_HMIX + (size_t)b * 512 + tid] = hm;

  if (tid < 256) {
    float4* ow = (float4*)&O[(size_t)b * 2048 + tid * 8];
    ow[0] = make_float4(ov[0], ov[1], ov[2], ov[3]);
    ow[1] = make_float4(ov[4], ov[5], ov[6], ov[7]);
    dout[OFF_OUT + (size_t)b * 256 + tid] = om;
  }
}

extern "C" void kernel_launch(void* const* d_in, const int* in_sizes, int n_in,
                              void* d_out, int out_size, void* d_ws, size_t ws_size,
                              hipStream_t stream) {
  const float* x    = (const float*)d_in[0];
  const float* h    = (const float*)d_in[1];
  const float* pi   = (const float*)d_in[2];
  const float* Wih  = (const float*)d_in[3];
  const float* Whh  = (const float*)d_in[4];
  const float* Wout = (const float*)d_in[5];
  float* out = (float*)d_out;
  u16* ws  = (u16*)d_ws;
  float* O = out + OFF_OK;  // out_k region doubles as f32 plane scratch

  k0_cvt<<<dim3(8320), 256, 0, stream>>>(x, h, Wih, Whh, Wout, ws);
  k1_gemm_tanh<<<dim3(32, 32), 256, 0, stream>>>(
      ws + WS_XB, ws + WS_HB, ws + WS_WIH, ws + WS_WHH, ws + WS_T);
  k2_gemm_out<<<dim3(32, 2, 8), 256, 0, stream>>>(ws + WS_T, ws + WS_WOUT, O);
  k3_epi<<<dim3(BATCH), 512, 0, stream>>>(pi, ws + WS_T, out);
}

// Round 5
// 220.621 us; speedup vs baseline: 1.1017x; 1.0275x over previous
//
#include <hip/hip_runtime.h>
#include <hip/hip_bf16.h>
#include <stdint.h>

typedef unsigned short u16;
typedef __attribute__((ext_vector_type(8))) short short8;
typedef __attribute__((ext_vector_type(4))) float f32x4;

#define BATCH 4096
// output region offsets (f32 elements) in d_out: out, h_mix, out_k, h_k
#define OFF_OUT  0
#define OFF_HMIX (BATCH * 256)
#define OFF_OK   (OFF_HMIX + BATCH * 512)
#define OFF_HK   (OFF_OK + BATCH * 256 * 8)

// ws layout (u16/bf16 elements): xb, hb, Wihb, Whhb, Woutb, Tb, Ob (~67 MB)
#define WS_XB   0
#define WS_HB   (2097152)
#define WS_WIH  (4194304)
#define WS_WHH  (6291456)
#define WS_WOUT (8388608)
#define WS_T    (8519680)    // 4096x4096 bf16 plane
#define WS_OB   (25296896)   // 4096x2048 bf16 plane

__device__ __forceinline__ float b2f(u16 v) {
  union { uint32_t u; float f; } c; c.u = ((uint32_t)v) << 16; return c.f;
}
__device__ __forceinline__ u16 f2b(float f) {
  union { float f; uint32_t u; } c; c.f = f;
  uint32_t u = c.u;
  return (u16)((u + 0x7fffu + ((u >> 16) & 1u)) >> 16);  // RNE
}

// async global->LDS, 16B per lane. LDS dest = wave-uniform base + lane*16.
__device__ __forceinline__ void gload16(const u16* g, u16* l) {
  __builtin_amdgcn_global_load_lds(
      (const __attribute__((address_space(1))) void*)g,
      (__attribute__((address_space(3))) void*)l, 16, 0, 0);
}

// ---------------------------------------------------------------------------
// K0: f32 -> bf16 conversion of x, h, W_ih, W_hh, W_out into ws.
// ---------------------------------------------------------------------------
__global__ __launch_bounds__(256) void k0_cvt(
    const float* __restrict__ x, const float* __restrict__ h,
    const float* __restrict__ Wih, const float* __restrict__ Whh,
    const float* __restrict__ Wout, u16* __restrict__ ws) {
  const int i = blockIdx.x * 256 + threadIdx.x;
  const float* src; int j; size_t dst;
  if      (i <  524288) { src = x;    j = i;           dst = WS_XB;   }
  else if (i < 1048576) { src = h;    j = i -  524288; dst = WS_HB;   }
  else if (i < 1572864) { src = Wih;  j = i - 1048576; dst = WS_WIH;  }
  else if (i < 2097152) { src = Whh;  j = i - 1572864; dst = WS_WHH;  }
  else                  { src = Wout; j = i - 2097152; dst = WS_WOUT; }
  const float4 v = ((const float4*)src)[j];
  ushort4 o;
  o.x = f2b(v.x); o.y = f2b(v.y); o.z = f2b(v.z); o.w = f2b(v.w);
  ((ushort4*)(ws + dst))[j] = o;
}

// ---------------------------------------------------------------------------
// K1: Tb[b][k*512+n] = tanh( x[b]·W_ih[k][n] + h[b]·W_hh[k][n] )  (bf16 plane)
// 4096x4096x1024 bf16 GEMM, tanh epilogue. 128x128 tile, BK=64, 4 waves 2x2.
// K-loop LDS is XOR-chunk-swizzled (bank-balanced at the 8-cyc data floor).
// Epilogue: LDS transpose (stride 136 u16, 16B-aligned rows) -> 16B stores.
// ---------------------------------------------------------------------------
__global__ __launch_bounds__(256) void k1_gemm_tanh(
    const u16* __restrict__ xb, const u16* __restrict__ hb,
    const u16* __restrict__ Wih, const u16* __restrict__ Whh,
    u16* __restrict__ Tb) {
  __shared__ u16 S[128 * 136];           // 34 KB: K-loop uses first 16K as As, next 8K... see below
  u16* As = S;                            // 128*64
  u16* Bs = S + 128 * 64;                 // 128*64
  const int tid  = threadIdx.x;
  const int lane = tid & 63;
  const int w    = tid >> 6;
  const int wm   = w >> 1, wn = w & 1;
  const int row0 = blockIdx.x * 128;
  const int col0 = blockIdx.y * 128;   // j = k*512 + n; 128 | 512 so tile is single-k
  const int kk   = col0 >> 9;
  const int nh0  = col0 & 511;
  const int sr   = tid >> 3;                                  // 0..31 staging row
  const int sc   = ((tid & 7) ^ ((tid >> 3) & 7)) * 8;        // swizzled source col
  const int ldsw = (w * 8) * 64;

  const u16* WihK = Wih + (size_t)kk * 512 * 512;
  const u16* WhhK = Whh + (size_t)kk * 512 * 512;

  f32x4 acc[4][4] = {};

  for (int kt = 0; kt < 16; ++kt) {
    const int kb = kt * 64;
    const u16* Asrc; const u16* Bsrc; int ko;
    if (kb < 512) { Asrc = xb; Bsrc = WihK; ko = kb; }
    else          { Asrc = hb; Bsrc = WhhK; ko = kb - 512; }
#pragma unroll
    for (int ro = 0; ro < 4; ++ro) {
      gload16(Asrc + (size_t)(row0 + ro * 32 + sr) * 512 + ko + sc, &As[ro * 32 * 64 + ldsw]);
      gload16(Bsrc + (size_t)(nh0  + ro * 32 + sr) * 512 + ko + sc, &Bs[ro * 32 * 64 + ldsw]);
    }
    __syncthreads();
    const int l7 = lane & 7, quad = lane >> 4, rl = lane & 15;
#pragma unroll
    for (int ks = 0; ks < 2; ++ks) {
      short8 af[4], bf[4];
      const int cs = ((ks * 4 + quad) ^ l7) * 8;  // swizzled chunk offset (elements)
#pragma unroll
      for (int i = 0; i < 4; ++i)
        af[i] = *(const short8*)&As[(wm * 64 + i * 16 + rl) * 64 + cs];
#pragma unroll
      for (int j = 0; j < 4; ++j)
        bf[j] = *(const short8*)&Bs[(wn * 64 + j * 16 + rl) * 64 + cs];
#pragma unroll
      for (int i = 0; i < 4; ++i)
#pragma unroll
        for (int j = 0; j < 4; ++j)
          acc[i][j] = __builtin_amdgcn_mfma_f32_16x16x32_bf16(af[i], bf[j], acc[i][j], 0, 0, 0);
    }
    __syncthreads();
  }

  // epilogue: tanh -> bf16 -> LDS transpose (stride 136) -> coalesced 16B stores
  const int quad = lane >> 4, cl = lane & 15;
#pragma unroll
  for (int i = 0; i < 4; ++i)
#pragma unroll
    for (int j = 0; j < 4; ++j)
#pragma unroll
      for (int r = 0; r < 4; ++r) {
        const int row = wm * 64 + i * 16 + quad * 4 + r;
        const int col = wn * 64 + j * 16 + cl;
        const float v = acc[i][j][r];
        const float e = __expf(2.0f * v);           // tanh, saturating, no NaN
        S[row * 136 + col] = f2b(1.0f - 2.0f / (e + 1.0f));
      }
  __syncthreads();
#pragma unroll
  for (int it = 0; it < 8; ++it) {
    const int idx = it * 256 + tid;   // 0..2047
    const int c = idx & 15;           // 16B chunk in row
    const int r = idx >> 4;           // row 0..127
    *(short8*)&Tb[(size_t)(row0 + r) * 4096 + col0 + c * 8] =
        *(const short8*)&S[r * 136 + c * 8];
  }
}

// ---------------------------------------------------------------------------
// K2: Ob[b][k*256+y] = sum_n Tb[b][k*512+n] * Wout[y][n]   (8 batched GEMMs)
// bf16 in / bf16 out (plane in ws). Same structure + transpose epilogue.
// ---------------------------------------------------------------------------
__global__ __launch_bounds__(256) void k2_gemm_out(
    const u16* __restrict__ Tb, const u16* __restrict__ Wout,
    u16* __restrict__ Ob) {
  __shared__ u16 S[128 * 136];
  u16* As = S;
  u16* Bs = S + 128 * 64;
  const int tid  = threadIdx.x;
  const int lane = tid & 63;
  const int w    = tid >> 6;
  const int wm   = w >> 1, wn = w & 1;
  const int row0 = blockIdx.x * 128;
  const int y0   = blockIdx.y * 128;
  const int kk   = blockIdx.z;
  const int sr   = tid >> 3;
  const int sc   = ((tid & 7) ^ ((tid >> 3) & 7)) * 8;
  const int ldsw = (w * 8) * 64;

  f32x4 acc[4][4] = {};

  for (int kt = 0; kt < 8; ++kt) {
    const int kb = kt * 64;
#pragma unroll
    for (int ro = 0; ro < 4; ++ro) {
      gload16(Tb + (size_t)(row0 + ro * 32 + sr) * 4096 + kk * 512 + kb + sc,
              &As[ro * 32 * 64 + ldsw]);
      gload16(Wout + (size_t)(y0 + ro * 32 + sr) * 512 + kb + sc,
              &Bs[ro * 32 * 64 + ldsw]);
    }
    __syncthreads();
    const int l7 = lane & 7, quad = lane >> 4, rl = lane & 15;
#pragma unroll
    for (int ks = 0; ks < 2; ++ks) {
      short8 af[4], bf[4];
      const int cs = ((ks * 4 + quad) ^ l7) * 8;
#pragma unroll
      for (int i = 0; i < 4; ++i)
        af[i] = *(const short8*)&As[(wm * 64 + i * 16 + rl) * 64 + cs];
#pragma unroll
      for (int j = 0; j < 4; ++j)
        bf[j] = *(const short8*)&Bs[(wn * 64 + j * 16 + rl) * 64 + cs];
#pragma unroll
      for (int i = 0; i < 4; ++i)
#pragma unroll
        for (int j = 0; j < 4; ++j)
          acc[i][j] = __builtin_amdgcn_mfma_f32_16x16x32_bf16(af[i], bf[j], acc[i][j], 0, 0, 0);
    }
    __syncthreads();
  }

  const int quad = lane >> 4, cl = lane & 15;
#pragma unroll
  for (int i = 0; i < 4; ++i)
#pragma unroll
    for (int j = 0; j < 4; ++j)
#pragma unroll
      for (int r = 0; r < 4; ++r) {
        const int row = wm * 64 + i * 16 + quad * 4 + r;
        const int col = wn * 64 + j * 16 + cl;
        S[row * 136 + col] = f2b(acc[i][j][r]);
      }
  __syncthreads();
#pragma unroll
  for (int it = 0; it < 8; ++it) {
    const int idx = it * 256 + tid;
    const int c = idx & 15;
    const int r = idx >> 4;
    *(short8*)&Ob[(size_t)(row0 + r) * 2048 + kk * 256 + y0 + c * 8] =
        *(const short8*)&S[r * 136 + c * 8];
  }
}

// ---------------------------------------------------------------------------
// K3: epilogue. Block b: reads Tb row + Ob row (bf16, ws), writes f32
// interleaved h_k / out_k (coalesced float4) + h_mix + out.
// ---------------------------------------------------------------------------
__global__ __launch_bounds__(512) void k3_epi(const float* __restrict__ pi,
                                              const u16* __restrict__ Tb,
                                              const u16* __restrict__ Ob,
                                              float* __restrict__ dout) {
  const int b   = blockIdx.x;
  const int tid = threadIdx.x;

  float pif[8];
#pragma unroll
  for (int k = 0; k < 8; ++k) pif[k] = pi[b * 8 + k];

  float tv[8]; float hm = 0.0f;
#pragma unroll
  for (int k = 0; k < 8; ++k) {
    const float v = b2f(Tb[(size_t)b * 4096 + k * 512 + tid]);
    tv[k] = v; hm += pif[k] * v;
  }
  float4* tw = (float4*)&dout[OFF_HK + (size_t)b * 4096 + tid * 8];
  tw[0] = make_float4(tv[0], tv[1], tv[2], tv[3]);
  tw[1] = make_float4(tv[4], tv[5], tv[6], tv[7]);
  dout[OFF_HMIX + (size_t)b * 512 + tid] = hm;

  if (tid < 256) {
    float ov[8]; float om = 0.0f;
#pragma unroll
    for (int k = 0; k < 8; ++k) {
      const float v = b2f(Ob[(size_t)b * 2048 + k * 256 + tid]);
      ov[k] = v; om += pif[k] * v;
    }
    float4* ow = (float4*)&dout[OFF_OK + (size_t)b * 2048 + tid * 8];
    ow[0] = make_float4(ov[0], ov[1], ov[2], ov[3]);
    ow[1] = make_float4(ov[4], ov[5], ov[6], ov[7]);
    dout[OFF_OUT + (size_t)b * 256 + tid] = om;
  }
}

extern "C" void kernel_launch(void* const* d_in, const int* in_sizes, int n_in,
                              void* d_out, int out_size, void* d_ws, size_t ws_size,
                              hipStream_t stream) {
  const float* x    = (const float*)d_in[0];
  const float* h    = (const float*)d_in[1];
  const float* pi   = (const float*)d_in[2];
  const float* Wih  = (const float*)d_in[3];
  const float* Whh  = (const float*)d_in[4];
  const float* Wout = (const float*)d_in[5];
  float* out = (float*)d_out;
  u16* ws  = (u16*)d_ws;

  k0_cvt<<<dim3(8320), 256, 0, stream>>>(x, h, Wih, Whh, Wout, ws);
  k1_gemm_tanh<<<dim3(32, 32), 256, 0, stream>>>(
      ws + WS_XB, ws + WS_HB, ws + WS_WIH, ws + WS_WHH, ws + WS_T);
  k2_gemm_out<<<dim3(32, 2, 8), 256, 0, stream>>>(ws + WS_T, ws + WS_WOUT, ws + WS_OB);
  k3_epi<<<dim3(BATCH), 512, 0, stream>>>(pi, ws + WS_T, ws + WS_OB, out);
}